// Round 13
// baseline (283.949 us; speedup 1.0000x reference)
//
#include <hip/hip_runtime.h>

// Correlation layer (FlowNet-style), max_displacement=4.
// in1,in2: [8,256,128,128] fp32 -> out: [8,81,128,128] fp32
// out[b, dy*9+dx, y, x] = sum_c in1[b,c,y,x] * in2[b,c,y+dy-4,x+dx-4] (0 if OOB)
//
// Round-13: MFMA-v2 = r7's banded-MFMA geometry (verified correct) + the
// r11/r12-proven pipeline: double-buffered LDS, stage(c+1)/compute(c)/ONE
// barrier per chunk, hoisted staging descriptors. r7's 280us was pure
// serialization (MfmaUtil 5.5%, VALU 8% — both idle); per-chunk demand is
// only 9 ds_read_b64 + 8 mfma per wave, so with staging latency hidden the
// kernel should drop well under the dot2 plateau (~97us).

constexpr int Bn = 8, Cn = 256, Hn = 128, Wn = 128, HW = Hn * Wn;
constexpr int ND = 9;
constexpr int KC  = 16;               // channels per k-chunk (one mfma k=16)
constexpr int NCH = Cn / KC;          // 16 chunks
constexpr int NT  = 576;              // 9 waves, wave = dy
constexpr int KS  = 20;               // LDS k-stride (16 k + 4 pad), f16 elems
constexpr int IN1E = 0;               // in1 region base (64 px)
constexpr int IN2E = 64 * KS;         // 1280: in2 region (9 rows x 80 px)
constexpr int ROWE = 80 * KS;         // 1600 elems per in2 row
constexpr int TOTE = IN2E + 9 * ROWE; // 15680 f16 = 31.4 KB per buffer
constexpr int NT1 = 128;              // in1 staging tasks (8 kp x 16 quads)
constexpr int NT2 = 9 * 8 * 20;      // 1440 in2 tasks (9 ri x 8 kp x 20 quads)
constexpr int NTASK = NT1 + NT2;      // 1568

typedef __fp16 half4 __attribute__((ext_vector_type(4)));
typedef float  f32x4 __attribute__((ext_vector_type(4)));
typedef __fp16 h2v   __attribute__((ext_vector_type(2)));

static __device__ __forceinline__ unsigned packh2(float a, float b) {
  h2v h = __builtin_amdgcn_cvt_pkrtz(a, b);   // a->low, b->high
  return __builtin_bit_cast(unsigned, h);
}

static __device__ __forceinline__ f32x4 mfma16(half4 a, half4 b, f32x4 c) {
#if __has_builtin(__builtin_amdgcn_mfma_f32_16x16x16f16)
  return __builtin_amdgcn_mfma_f32_16x16x16f16(a, b, c, 0, 0, 0);
#else
  f32x4 d;
  asm volatile("v_mfma_f32_16x16x16_f16 %0, %1, %2, %3"
               : "=v"(d) : "v"(a), "v"(b), "v"(c));
  return d;
#endif
}

__global__ __launch_bounds__(NT, 8) void corr_kernel(
    const float* __restrict__ in1, const float* __restrict__ in2,
    float* __restrict__ out)
{
  __shared__ __align__(16) __fp16 sm[2 * TOTE];   // 62.7 KB (double-buffered)

  // XCD swizzle: 2048 blocks, bijective (2048 % 8 == 0). Each XCD gets one
  // batch; within an XCD consecutive blocks walk (xh, y) -> in2 rows L2-hot.
  int bid = blockIdx.x;
  bid = (bid & 7) * 256 + (bid >> 3);
  const int b  = bid >> 8;
  const int y  = (bid >> 1) & 127;
  const int xh = bid & 1;
  const int X0 = xh << 6;              // 0 or 64
  const int XP0 = X0 - 4;              // x' origin (stored phase -4)

  const int tid = threadIdx.x;
  const int dy  = tid >> 6;            // wave id = dy
  const int l   = tid & 63;
  const int n   = l & 15;              // mfma n index (px col within tile)
  const int g   = l >> 4;              // mfma k-group / m-row group

  const size_t gbase = (size_t)b * Cn * HW;

  // ---- hoisted staging descriptors: up to 3 tasks/thread ----
  // task: load float4 pair (2 ch x 4 px), pack f16x2 (k-pair), write 4
  // strided b32 into the k-major LDS tile. Invalid tasks skipped (slots
  // stay zero from the one-time pre-zero: OOB rows/halo cols).
  const float* sptr[3];
  int  soff[3];
  bool svalid[3];
#pragma unroll
  for (int s = 0; s < 3; ++s) {
    const int t = tid + s * NT;
    bool v = t < NTASK;
    const float* p = in1;
    int off = 0;
    if (v) {
      if (t < NT1) {                   // in1: kp(8) x quad(16)
        const int kp = t & 7, qi = t >> 3;
        p   = in1 + gbase + (size_t)(2 * kp) * HW + y * Wn + X0 + 4 * qi;
        off = IN1E + (4 * qi) * KS + 2 * kp;
      } else {                         // in2: ri(9) x kp(8) x quad(20)
        const int t2 = t - NT1;
        const int ri = t2 / 160, rem = t2 - ri * 160;
        const int kp = rem & 7, qi = rem >> 3;
        const int xp = XP0 + 4 * qi;   // global x' of quad start
        const int r  = y + ri - 4;
        v = (unsigned)r < (unsigned)Hn && (unsigned)xp <= (unsigned)(Wn - 4);
        p   = in2 + gbase + (size_t)(2 * kp) * HW +
              (size_t)(v ? r : 0) * Wn + (v ? xp : 0);
        off = IN2E + ri * ROWE + (4 * qi) * KS + 2 * kp;
      }
    }
    sptr[s] = p; soff[s] = off; svalid[s] = v;
  }

  // ---- pre-zero BOTH buffers once (OOB slots never rewritten) ----
  for (int i = tid; i < (2 * TOTE) / 8; i += NT)
    *(uint4*)&sm[i * 8] = uint4{0, 0, 0, 0};

  // per-lane fragment offsets (constant across chunks)
  const int fragoff = n * KS + 4 * g;  // px-col n, k = 4g..4g+3
  const int offA = IN1E + fragoff;
  const int offB = IN2E + dy * ROWE + fragoff;

  f32x4 acc[4][2];
#pragma unroll
  for (int w = 0; w < 4; ++w) {
    acc[w][0] = f32x4{0.f, 0.f, 0.f, 0.f};
    acc[w][1] = f32x4{0.f, 0.f, 0.f, 0.f};
  }

  __syncthreads();                     // pre-zero visible

  // ---- prologue: stage chunk 0 into buffer 0 ----
#pragma unroll
  for (int s = 0; s < 3; ++s) {
    if (svalid[s]) {
      const float4 f0 = *(const float4*)sptr[s];
      const float4 f1 = *(const float4*)(sptr[s] + HW);
      const int o = soff[s];
      *(unsigned*)&sm[o         ] = packh2(f0.x, f1.x);
      *(unsigned*)&sm[o +     KS] = packh2(f0.y, f1.y);
      *(unsigned*)&sm[o + 2 * KS] = packh2(f0.z, f1.z);
      *(unsigned*)&sm[o + 3 * KS] = packh2(f0.w, f1.w);
    }
  }
  __syncthreads();

  for (int c = 0; c < NCH; ++c) {
    // ---- stage chunk c+1 into the other buffer (no barrier before compute:
    //      global-load latency hides under this chunk's reads+mfma) ----
    if (c + 1 < NCH) {
      const int nb = ((c + 1) & 1) * TOTE;
      const size_t ofs = (size_t)(c + 1) * KC * HW;
#pragma unroll
      for (int s = 0; s < 3; ++s) {
        if (svalid[s]) {
          const float* p = sptr[s] + ofs;
          const float4 f0 = *(const float4*)p;
          const float4 f1 = *(const float4*)(p + HW);
          const int o = nb + soff[s];
          *(unsigned*)&sm[o         ] = packh2(f0.x, f1.x);
          *(unsigned*)&sm[o +     KS] = packh2(f0.y, f1.y);
          *(unsigned*)&sm[o + 2 * KS] = packh2(f0.z, f1.z);
          *(unsigned*)&sm[o + 3 * KS] = packh2(f0.w, f1.w);
        }
      }
    }

    // ---- compute chunk c: 9 ds_read_b64 + 8 mfma ----
    const int cb = (c & 1) * TOTE;
    half4 Bf[5];
#pragma unroll
    for (int sw = 0; sw < 5; ++sw)
      Bf[sw] = *(const half4*)&sm[cb + offB + sw * 16 * KS];
#pragma unroll
    for (int w = 0; w < 4; ++w) {
      const half4 Af = *(const half4*)&sm[cb + offA + w * 16 * KS];
      acc[w][0] = mfma16(Af, Bf[w],     acc[w][0]);
      acc[w][1] = mfma16(Af, Bf[w + 1], acc[w][1]);
    }
    __syncthreads();   // buf^1 writes visible; buf reads done
  }

  // ---- epilogue: predicated dword stores over the valid band ----
  // D[m][nn]: lane holds m = 4g+q (q=0..3), nn = n; dx = 16t + n - m.
  const size_t obase = ((size_t)(b * 81 + dy * 9) * Hn + y) * Wn;
#pragma unroll
  for (int w = 0; w < 4; ++w) {
#pragma unroll
    for (int t = 0; t < 2; ++t) {
#pragma unroll
      for (int q = 0; q < 4; ++q) {
        const int m  = 4 * g + q;
        const int dx = 16 * t + n - m;
        if ((unsigned)dx <= 8u)
          out[obase + (size_t)dx * HW + X0 + 16 * w + m] = acc[w][t][q];
      }
    }
  }
}

extern "C" void kernel_launch(void* const* d_in, const int* in_sizes, int n_in,
                              void* d_out, int out_size, void* d_ws, size_t ws_size,
                              hipStream_t stream) {
  const float* in1 = (const float*)d_in[0];
  const float* in2 = (const float*)d_in[1];
  float* out = (float*)d_out;
  dim3 grid(Bn * Hn * 2);   // 2048 blocks: (batch, y, x-half)
  dim3 block(NT);           // 576 threads = 9 waves (wave = dy)
  hipLaunchKernelGGL(corr_kernel, grid, block, 0, stream, in1, in2, out);
}

// Round 14
// 97.128 us; speedup vs baseline: 2.9235x; 2.9235x over previous
//
#include <hip/hip_runtime.h>

// Correlation layer (FlowNet-style), max_displacement=4.
// in1,in2: [8,256,128,128] fp32 -> out: [8,81,128,128] fp32
// out[b, dy*9+dx, y, x] = sum_c in1[b,c,y,x] * in2[b,c,y+dy-4,x+dx-4] (0 if OOB)
//
// Round-14: r12 (best, 97.2us) with v_dot2_f32_f16 -> v_pk_fma_f16.
//   Measured VALU busy (46us) matches a 4-cyc dot2 model, not 2-cyc; packed
//   f16 FMA is full-rate. Accumulate f16x2 with halves = even/odd-channel
//   partial sums (k-split); epilogue sums lo+hi in f32. Everything else
//   (dbuf pipeline, hoisted descriptors, padding, swizzle) unchanged.

constexpr int Bn = 8, Cn = 256, Hn = 128, Wn = 128, HW = Hn * Wn;
constexpr int Dd = 4, ND = 9;
constexpr int KC = 8, NP = KC / 2;     // 4 f16x2 channel-pairs per chunk
constexpr int NCH = Cn / KC;           // 32 chunks
constexpr int KCHW = KC * HW;
constexpr int NT = 576;                // 9 waves: dy(9) x (2 rows x 32 quads)
constexpr int S1P = 2 * Wn + 4;        // s1 pair stride 260 u32
constexpr int W2  = Wn + 12;           // s2 row width 140 u32
constexpr int S1  = NP * S1P;          // 1040 u32
constexpr int S2  = NP * 10 * W2;      // 5600 u32
constexpr int BUF = S1 + S2;           // 6640 u32 -> 2 buffers = 53.1 KB
constexpr int NT1 = NP * 2 * 32;       // 256 in1 staging quad-tasks
constexpr int NT2 = NP * 10 * 32;      // 1280 in2 staging quad-tasks
constexpr int NTASK = NT1 + NT2;       // 1536 (2.67 per thread)

typedef __fp16 h2v __attribute__((ext_vector_type(2)));

static __device__ __forceinline__ unsigned packh2(float a, float b) {
  h2v h = __builtin_amdgcn_cvt_pkrtz(a, b);   // a->low, b->high
  return __builtin_bit_cast(unsigned, h);
}

__global__ __launch_bounds__(NT) void corr_kernel(
    const float* __restrict__ in1, const float* __restrict__ in2,
    float* __restrict__ out)
{
  __shared__ __align__(16) unsigned lds[2 * BUF];   // 53.1 KB

  // XCD-chunked swizzle: 512 blocks, 8 XCDs, bijective (512 % 8 == 0).
  int bid = blockIdx.x;
  bid = (bid & 7) * 64 + (bid >> 3);
  const int b  = bid >> 6;
  const int y0 = (bid & 63) << 1;

  const int tid  = threadIdx.x;
  const int dy   = tid >> 6;           // 0..8 (wave id)
  const int lane = tid & 63;
  const int row  = lane >> 5;          // 0..1
  const int x0   = (lane & 31) << 2;   // 4 consecutive px
  const int srow = dy + row;           // staged in2 row 0..9
  const size_t base = (size_t)b * Cn * HW;

  // ---- hoisted staging descriptors: up to 3 quad-tasks/thread ----
  const float* psrc[3];
  int  pdst[3];
  int  okm = 0;                        // bit s: in-bounds (write data vs zeros)
#pragma unroll
  for (int s = 0; s < 3; ++s) {
    const int t = tid + s * NT;
    if (t >= NTASK) { psrc[s] = in1; pdst[s] = 0; continue; }
    if (t < NT1) {                     // in1: p(4) x row(2) x quad(32)
      const int p = t >> 6, yy = (t >> 5) & 1, gx = (t & 31) << 2;
      psrc[s] = in1 + base + (size_t)(2 * p) * HW + (y0 + yy) * Wn + gx;
      pdst[s] = p * S1P + yy * Wn + gx;
      okm |= 1 << s;
    } else {                           // in2: p(4) x row(10) x quad(32)
      const int g = t - NT1;
      const int p = g / 320, rem = g - p * 320;
      const int r = rem >> 5, gx = (rem & 31) << 2;
      const int gy = y0 + r - Dd;
      const bool ok = (unsigned)gy < (unsigned)Hn;
      psrc[s] = in2 + base + (size_t)(2 * p) * HW +
                (size_t)(ok ? gy : 0) * Wn + gx;
      pdst[s] = S1 + (p * 10 + r) * W2 + 4 + gx;
      okm |= (ok ? 1 : 0) << s;
    }
  }

  // ---- zero x-halo quads of BOTH buffers (cols 0..3,132..135): only here ----
  for (int i = tid; i < 2 * NP * 10 * 2; i += NT) {
    const int bf = i / (NP * 10 * 2), rem = i - bf * (NP * 10 * 2);
    const int pr = rem >> 1, side = rem & 1;
    *(uint4*)&lds[bf * BUF + S1 + pr * W2 + side * 132] = uint4{0, 0, 0, 0};
  }

  // f16x2 accumulators: halves = even/odd channel partial sums (k-split)
  h2v acc[ND][4];
#pragma unroll
  for (int dx = 0; dx < ND; ++dx)
#pragma unroll
    for (int j = 0; j < 4; ++j) acc[dx][j] = h2v{(__fp16)0.f, (__fp16)0.f};

  // ---- prologue: stage chunk 0 into buffer 0 ----
#pragma unroll
  for (int s = 0; s < 3; ++s) {
    if (s == 2 && tid >= NTASK - 2 * NT) continue;   // wave-uniform tail
    const float4 f0 = *(const float4*)psrc[s];
    const float4 f1 = *(const float4*)(psrc[s] + HW);
    uint4 w;
    w.x = packh2(f0.x, f1.x); w.y = packh2(f0.y, f1.y);
    w.z = packh2(f0.z, f1.z); w.w = packh2(f0.w, f1.w);
    if (!((okm >> s) & 1)) w = uint4{0, 0, 0, 0};
    *(uint4*)&lds[pdst[s]] = w;
  }
  __syncthreads();

  for (int c = 0; c < NCH; ++c) {
    // ---- stage chunk c+1 into the other buffer (no barrier before compute:
    //      its global-load latency hides under this chunk's FMA burst) ----
    if (c + 1 < NCH) {
      const unsigned nb = ((c + 1) & 1) * BUF;
      const size_t ofs = (size_t)(c + 1) * KCHW;
#pragma unroll
      for (int s = 0; s < 3; ++s) {
        if (s == 2 && tid >= NTASK - 2 * NT) continue;
        const float* sp = psrc[s] + ofs;
        const float4 f0 = *(const float4*)sp;
        const float4 f1 = *(const float4*)(sp + HW);
        uint4 w;
        w.x = packh2(f0.x, f1.x); w.y = packh2(f0.y, f1.y);
        w.z = packh2(f0.z, f1.z); w.w = packh2(f0.w, f1.w);
        if (!((okm >> s) & 1)) w = uint4{0, 0, 0, 0};
        *(uint4*)&lds[nb + pdst[s]] = w;
      }
    }

    // ---- compute chunk c from current buffer: per pair 4x ds_read_b128 ->
    //      36 v_pk_fma_f16 (72 MACs) ----
    const unsigned* bp0 = &lds[(c & 1) * BUF];
#pragma unroll
    for (int p = 0; p < NP; ++p) {
      const uint4 av = *(const uint4*)(bp0 + p * S1P + row * Wn + x0);
      const unsigned* bp = bp0 + S1 + (p * 10 + srow) * W2 + x0;
      const uint4 b0 = *(const uint4*)bp;
      const uint4 b1 = *(const uint4*)(bp + 4);
      const uint4 b2 = *(const uint4*)(bp + 8);
      const unsigned aau[4]  = {av.x, av.y, av.z, av.w};
      const unsigned bbu[12] = {b0.x, b0.y, b0.z, b0.w, b1.x, b1.y,
                                b1.z, b1.w, b2.x, b2.y, b2.z, b2.w};
      h2v aa[4], bb[12];
#pragma unroll
      for (int j = 0; j < 4; ++j)  aa[j] = __builtin_bit_cast(h2v, aau[j]);
#pragma unroll
      for (int j = 0; j < 12; ++j) bb[j] = __builtin_bit_cast(h2v, bbu[j]);
#pragma unroll
      for (int dx = 0; dx < ND; ++dx) {
#pragma unroll
        for (int j = 0; j < 4; ++j)
          acc[dx][j] = aa[j] * bb[dx + j] + acc[dx][j];   // v_pk_fma_f16
      }
    }
    __syncthreads();   // buf^1 writes visible; buf reads done
  }

  // ---- epilogue: lo+hi in f32, coalesced float4 stores ----
#pragma unroll
  for (int dx = 0; dx < ND; ++dx) {
    float4 v;
    v.x = (float)acc[dx][0].x + (float)acc[dx][0].y;
    v.y = (float)acc[dx][1].x + (float)acc[dx][1].y;
    v.z = (float)acc[dx][2].x + (float)acc[dx][2].y;
    v.w = (float)acc[dx][3].x + (float)acc[dx][3].y;
    const size_t o =
        (((size_t)b * (ND * ND) + dy * ND + dx) * Hn + (y0 + row)) * Wn + x0;
    *(float4*)&out[o] = v;
  }
}

extern "C" void kernel_launch(void* const* d_in, const int* in_sizes, int n_in,
                              void* d_out, int out_size, void* d_ws, size_t ws_size,
                              hipStream_t stream) {
  const float* in1 = (const float*)d_in[0];
  const float* in2 = (const float*)d_in[1];
  float* out = (float*)d_out;
  dim3 grid(Bn * (Hn / 2));   // 512 blocks: (batch, y-pair)
  dim3 block(NT);             // 576 threads = 9 waves
  hipLaunchKernelGGL(corr_kernel, grid, block, 0, stream, in1, in2, out);
}